// Round 6
// baseline (2922.116 us; speedup 1.0000x reference)
//
#include <hip/hip_runtime.h>

// RISnetPIv2 fully-fused persistent kernel. B=128, U=16, A=1024.
// Factored features: ll[B,U,A,8] (REGISTERS, packed bf16), lg[B,U,8], gl[B,A,8]
// (LDS), gg[B,8]. Grid 1024 = 128 b x 8 a-blocks; block 256 thr = 1 a x 8 u per
// thread (uh = tid>>7 selects u-half, aIdx = tid&127). Co-residency: LDS 40064B
// -> 4 blocks/CU, launch_bounds(256,4) -> <=128 VGPR -> 4 waves/SIMD. Per-layer
// cross-block sync: only the 8 blocks sharing b, via device-scope counter.
// f3 skip tile in LDS; f1 ll recomputed from channel at L5; gl1/gl3 snapshots
// + lg/gg per-layer sums in global ws (tiny).

#define NB 128
#define NU 16
#define NA 1024

static constexpr float PI_F   = 3.14159265358979323846f;
static constexpr float INV_A  = 1.0f / 1024.0f;
static constexpr float INV_UA = 1.0f / 16384.0f;
static constexpr float INV_U  = 1.0f / 16.0f;

__device__ __forceinline__ float wsum(float v) {
#pragma unroll
    for (int d = 1; d < 64; d <<= 1) v += __shfl_xor(v, d, 64);
    return v;
}
__device__ __forceinline__ unsigned short f2bf(float f) {  // RNE
    unsigned int u = __float_as_uint(f);
    u += 0x7fffu + ((u >> 16) & 1u);
    return (unsigned short)(u >> 16);
}
__device__ __forceinline__ unsigned int pack2(float a, float b) {
    return (unsigned int)f2bf(a) | ((unsigned int)f2bf(b) << 16);
}
__device__ __forceinline__ float bflo(unsigned int u) { return __uint_as_float(u << 16); }
__device__ __forceinline__ float bfhi(unsigned int u) { return __uint_as_float(u & 0xffff0000u); }
__device__ __forceinline__ float aload(float* p) {
    return __hip_atomic_load(p, __ATOMIC_RELAXED, __HIP_MEMORY_SCOPE_AGENT);
}

__device__ __forceinline__ void spin_wait(int* cnt, int idx, int tid) {
    if (tid == 0) {
        int it = 0;
        while (__hip_atomic_load(cnt + idx, __ATOMIC_ACQUIRE,
                                 __HIP_MEMORY_SCOPE_AGENT) < 8) {
            __builtin_amdgcn_s_sleep(2);
            if (++it > (1 << 22)) break;  // safety valve: terminate, not hang
        }
    }
    __syncthreads();
}

// gg butterfly+atomic, lg combine+atomic, glds two-step update (+snapshot),
// then release-arrive on this layer's counter.
__device__ __forceinline__ void layer_tail(
    int li, int b, int a, int aIdx, int uh, int tid,
    const float* glacc, const float* ggacc,
    float* red, float* glds,
    float* lg, float* gg, int* cnt, float* snap)
{
#pragma unroll
    for (int c = 0; c < 8; ++c) {
        float v = wsum(ggacc[c]);
        if ((tid & 63) == 0) atomicAdd(gg + (li * NB + b) * 8 + c, v);
    }
    __syncthreads();                       // red lg-partials complete
    if (tid < 128) {
        int u = tid >> 3, c = tid & 7;
        int base = (u < 8 ? 0 : 2) * 64 + (u & 7) * 8 + c;
        float v = red[base] + red[base + 64];
        atomicAdd(lg + ((size_t)(li * NB + b) * NU + u) * 8 + c, v);
    }
    __syncthreads();
    if (uh == 1) {
#pragma unroll
        for (int c = 0; c < 8; ++c) glds[aIdx * 8 + c] = glacc[c];
    }
    __syncthreads();
    if (uh == 0) {
#pragma unroll
        for (int c = 0; c < 8; ++c) {
            float g = (glacc[c] + glds[aIdx * 8 + c]) * INV_U;
            glds[aIdx * 8 + c] = g;
            if (snap) snap[((size_t)b * NA + a) * 8 + c] = g;
        }
    }
    __threadfence();
    __syncthreads();
    if (tid == 0)
        __hip_atomic_fetch_add(cnt + li * NB + b, 1, __ATOMIC_RELEASE,
                               __HIP_MEMORY_SCOPE_AGENT);
}

__global__ __launch_bounds__(256, 4) void risnet_fused(
    const float* __restrict__ ch, const float* __restrict__ W1,
    const float* __restrict__ b1, const float* __restrict__ Wm,
    const float* __restrict__ bm, const float* __restrict__ W8,
    const float* __restrict__ b8, float* __restrict__ out,
    float* lg, float* gg, float* gl1, float* gl3, int* cnt)
{
    __shared__ unsigned int f3p[16 * 128 * 4];   // 32768 B: f3 ll, packed bf16
    __shared__ float glds[128 * 8];              //  4096 B: current gl (mean)
    __shared__ float baseds[16 * 32];            //  2048 B
    __shared__ float red[288];                   //  1152 B  (total 40064)

    const int tid  = threadIdx.x;
    const int aIdx = tid & 127;
    const int uh   = tid >> 7;
    const int wv   = tid >> 6;
    const int b    = blockIdx.x >> 3;
    const int ab   = blockIdx.x & 7;
    const int a    = ab * 128 + aIdx;
    const int u0   = uh * 8;

    unsigned int llp[32];          // [ul][chpair]: 8 u x 8 ch packed bf16
    float glacc[8], ggacc[8];

    // ================= Layer 1 =================
    {
        float chv[32];             // [c][ul]
#pragma unroll
        for (int c = 0; c < 4; ++c)
#pragma unroll
            for (int ul = 0; ul < 8; ++ul)
                chv[c * 8 + ul] = ch[((size_t)(b * 4 + c) * NU + (u0 + ul)) * NA + a];
#pragma unroll
        for (int i = 0; i < 8; ++i) { glacc[i] = 0.f; ggacc[i] = 0.f; }
#pragma unroll
        for (int ul = 0; ul < 8; ++ul) {
            float yA[16];
#pragma unroll
            for (int o = 0; o < 16; ++o) yA[o] = b1[o];
#pragma unroll
            for (int c = 0; c < 4; ++c) {
                float xv = chv[c * 8 + ul];
#pragma unroll
                for (int o = 0; o < 16; ++o)
                    yA[o] = fmaf(xv, W1[((o >> 3) * 4 + c) * 8 + (o & 7)], yA[o]);
            }
#pragma unroll
            for (int o = 0; o < 16; ++o) yA[o] = fmaxf(yA[o], 0.f);
            llp[ul * 4 + 0] = pack2(yA[0], yA[1]);
            llp[ul * 4 + 1] = pack2(yA[2], yA[3]);
            llp[ul * 4 + 2] = pack2(yA[4], yA[5]);
            llp[ul * 4 + 3] = pack2(yA[6], yA[7]);
#pragma unroll
            for (int c = 0; c < 8; ++c) {
                float v = wsum(yA[8 + c]);
                if ((tid & 63) == 0) red[wv * 64 + ul * 8 + c] = v;
            }
            float yB[16];
#pragma unroll
            for (int o = 0; o < 16; ++o) yB[o] = b1[o + 16];
#pragma unroll
            for (int c = 0; c < 4; ++c) {
                float xv = chv[c * 8 + ul];
#pragma unroll
                for (int o = 0; o < 16; ++o)
                    yB[o] = fmaf(xv, W1[((2 + (o >> 3)) * 4 + c) * 8 + (o & 7)], yB[o]);
            }
#pragma unroll
            for (int o = 0; o < 16; ++o) yB[o] = fmaxf(yB[o], 0.f);
#pragma unroll
            for (int i = 0; i < 8; ++i) { glacc[i] += yB[i]; ggacc[i] += yB[8 + i]; }
        }
        layer_tail(0, b, a, aIdx, uh, tid, glacc, ggacc, red, glds, lg, gg, cnt, gl1);
    }

    // ================= Layers 2..7 =================
#pragma unroll 1
    for (int li = 1; li <= 6; ++li) {
        const bool isL3 = (li == 2), isL5 = (li == 4), isL6 = (li == 5);
        const float* Wl = Wm + (size_t)(li - 1) * 1024;
        const float* bl = bm + (size_t)(li - 1) * 32;

        spin_wait(cnt, (li - 1) * NB + b, tid);

        // stage lg/gg MEANS into red[0..135]
        if (tid < 136) {
            float v;
            if (tid < 128) {
                int u = tid >> 3, c = tid & 7;
                v = aload(lg + ((size_t)((li - 1) * NB + b) * NU + u) * 8 + c) * INV_A;
                if (isL6)
                    v = (v + aload(lg + ((size_t)b * NU + u) * 8 + c) * INV_A) * 0.5f;
            } else {
                int c = tid - 128;
                v = aload(gg + ((li - 1) * NB + b) * 8 + c) * INV_UA;
                if (isL6) v = (v + aload(gg + b * 8 + c) * INV_UA) * 0.5f;
            }
            red[tid] = v;
        }
        // cgl[32] from glds (+ L6 skip with gl1 snapshot)
        float g[8];
#pragma unroll
        for (int c = 0; c < 8; ++c) g[c] = glds[aIdx * 8 + c];
        if (isL6) {
#pragma unroll
            for (int c = 0; c < 8; ++c)
                g[c] = (g[c] + gl1[((size_t)b * NA + a) * 8 + c]) * 0.5f;
        }
        float cgl[32];
#pragma unroll
        for (int o = 0; o < 32; ++o) cgl[o] = 0.f;
#pragma unroll
        for (int c = 0; c < 8; ++c) {
            float gc = g[c];
#pragma unroll
            for (int o = 0; o < 32; ++o)
                cgl[o] = fmaf(gc, Wl[((o >> 3) * 32 + 16 + c) * 8 + (o & 7)], cgl[o]);
        }
        __syncthreads();
        // base[16][32]
        {
            int u = tid >> 4, op = tid & 15;
#pragma unroll
            for (int h = 0; h < 2; ++h) {
                int o = op + h * 16;
                float v = bl[o];
#pragma unroll
                for (int c = 0; c < 8; ++c)
                    v = fmaf(red[u * 8 + c], Wl[((o >> 3) * 32 + 8 + c) * 8 + (o & 7)], v);
#pragma unroll
                for (int c = 0; c < 8; ++c)
                    v = fmaf(red[128 + c], Wl[((o >> 3) * 32 + 24 + c) * 8 + (o & 7)], v);
                baseds[u * 32 + o] = v;
            }
        }
        __syncthreads();

#pragma unroll
        for (int i = 0; i < 8; ++i) { glacc[i] = 0.f; ggacc[i] = 0.f; }
        float xcn[4];
        if (isL5) {
#pragma unroll
            for (int c = 0; c < 4; ++c)
                xcn[c] = ch[((size_t)(b * 4 + c) * NU + u0) * NA + a];
        }
#pragma unroll
        for (int ul = 0; ul < 8; ++ul) {
            const int u = u0 + ul;
            float x[8];
            x[0] = bflo(llp[ul * 4 + 0]); x[1] = bfhi(llp[ul * 4 + 0]);
            x[2] = bflo(llp[ul * 4 + 1]); x[3] = bfhi(llp[ul * 4 + 1]);
            x[4] = bflo(llp[ul * 4 + 2]); x[5] = bfhi(llp[ul * 4 + 2]);
            x[6] = bflo(llp[ul * 4 + 3]); x[7] = bfhi(llp[ul * 4 + 3]);
            float xc[4];
            if (isL5) {
#pragma unroll
                for (int c = 0; c < 4; ++c) xc[c] = xcn[c];
                if (ul < 7) {
#pragma unroll
                    for (int c = 0; c < 4; ++c)
                        xcn[c] = ch[((size_t)(b * 4 + c) * NU + (u + 1)) * NA + a];
                }
            }
            float yA[16];
#pragma unroll
            for (int o = 0; o < 16; ++o) yA[o] = cgl[o] + baseds[u * 32 + o];
#pragma unroll
            for (int c = 0; c < 8; ++c) {
                float xv = x[c];
#pragma unroll
                for (int o = 0; o < 16; ++o)
                    yA[o] = fmaf(xv, Wl[((o >> 3) * 32 + c) * 8 + (o & 7)], yA[o]);
            }
#pragma unroll
            for (int o = 0; o < 16; ++o) yA[o] = fmaxf(yA[o], 0.f);
            float o8[8];
            if (isL5) {
                float t[8];
#pragma unroll
                for (int i = 0; i < 8; ++i) t[i] = b1[i];
#pragma unroll
                for (int c = 0; c < 4; ++c)
#pragma unroll
                    for (int i = 0; i < 8; ++i)
                        t[i] = fmaf(xc[c], W1[c * 8 + i], t[i]);
#pragma unroll
                for (int i = 0; i < 8; ++i)
                    o8[i] = (yA[i] + fmaxf(t[i], 0.f)) * 0.5f;
            } else {
#pragma unroll
                for (int i = 0; i < 8; ++i) o8[i] = yA[i];
            }
            llp[ul * 4 + 0] = pack2(o8[0], o8[1]);
            llp[ul * 4 + 1] = pack2(o8[2], o8[3]);
            llp[ul * 4 + 2] = pack2(o8[4], o8[5]);
            llp[ul * 4 + 3] = pack2(o8[6], o8[7]);
            if (isL3) {
                uint4 v;
                v.x = llp[ul * 4 + 0]; v.y = llp[ul * 4 + 1];
                v.z = llp[ul * 4 + 2]; v.w = llp[ul * 4 + 3];
                *reinterpret_cast<uint4*>(&f3p[(u * 128 + aIdx) * 4]) = v;
            }
#pragma unroll
            for (int c = 0; c < 8; ++c) {
                float v = wsum(yA[8 + c]);
                if ((tid & 63) == 0) red[wv * 64 + ul * 8 + c] = v;
            }
            float yB[16];
#pragma unroll
            for (int o = 0; o < 16; ++o) yB[o] = cgl[o + 16] + baseds[u * 32 + 16 + o];
#pragma unroll
            for (int c = 0; c < 8; ++c) {
                float xv = x[c];
#pragma unroll
                for (int o = 0; o < 16; ++o)
                    yB[o] = fmaf(xv, Wl[((2 + (o >> 3)) * 32 + c) * 8 + (o & 7)], yB[o]);
            }
#pragma unroll
            for (int o = 0; o < 16; ++o) yB[o] = fmaxf(yB[o], 0.f);
#pragma unroll
            for (int i = 0; i < 8; ++i) { glacc[i] += yB[i]; ggacc[i] += yB[8 + i]; }
        }
        layer_tail(li, b, a, aIdx, uh, tid, glacc, ggacc, red, glds, lg, gg, cnt,
                   isL3 ? gl3 : nullptr);
    }

    // ================= Layer 8 =================
    spin_wait(cnt, 6 * NB + b, tid);
    if (tid < 8) {
        int c = tid;
        float s7 = 0.f, s3 = 0.f;
#pragma unroll
        for (int u = 0; u < NU; ++u) {
            s7 += aload(lg + ((size_t)(6 * NB + b) * NU + u) * 8 + c);
            s3 += aload(lg + ((size_t)(2 * NB + b) * NU + u) * 8 + c);
        }
        float g7 = aload(gg + (6 * NB + b) * 8 + c);
        float g3 = aload(gg + (2 * NB + b) * 8 + c);
        red[256 + c] = ((s7 + s3) * INV_A * 0.5f * INV_U) * W8[8 + c]
                     + ((g7 + g3) * INV_UA * 0.5f) * W8[24 + c];
    }
    float p = 0.f;
#pragma unroll
    for (int ul = 0; ul < 8; ++ul) {
        const int u = u0 + ul;
        uint4 f3v = *reinterpret_cast<const uint4*>(&f3p[(u * 128 + aIdx) * 4]);
        unsigned int w3[4] = {f3v.x, f3v.y, f3v.z, f3v.w};
#pragma unroll
        for (int cp = 0; cp < 4; ++cp) {
            unsigned int w7 = llp[ul * 4 + cp];
            p += 0.5f * (bflo(w7) + bflo(w3[cp])) * W8[cp * 2]
               + 0.5f * (bfhi(w7) + bfhi(w3[cp])) * W8[cp * 2 + 1];
        }
    }
    red[tid] = p;
    __syncthreads();
    if (uh == 0) {
        float asum = (red[tid] + red[tid + 128]) * INV_U;
        float sb = b8[0];
#pragma unroll
        for (int c = 0; c < 8; ++c) sb += red[256 + c];
#pragma unroll
        for (int c = 0; c < 8; ++c)
            asum += 0.5f * (glds[aIdx * 8 + c] + gl3[((size_t)b * NA + a) * 8 + c])
                  * W8[16 + c];
        out[(size_t)b * NA + a] = (asum + sb) * PI_F;
    }
}

extern "C" void kernel_launch(void* const* d_in, const int* in_sizes, int n_in,
                              void* d_out, int out_size, void* d_ws, size_t ws_size,
                              hipStream_t stream) {
    const float* channel = (const float*)d_in[0];
    const float* W1 = (const float*)d_in[1];
    const float* b1 = (const float*)d_in[2];
    const float* Wm = (const float*)d_in[3];
    const float* bm = (const float*)d_in[4];
    const float* W8 = (const float*)d_in[5];
    const float* b8 = (const float*)d_in[6];

    float* lg = (float*)d_ws;                    // [7][128][16][8] = 114688 f
    float* gg = lg + 7 * NB * NU * 8;            // [7][128][8]     = 7168 f
    int* cnt  = (int*)(gg + 7 * NB * 8);         // [7][128]        = 896 i
    float* gl1 = (float*)(cnt + 7 * NB);         // [128][1024][8]
    float* gl3 = gl1 + (size_t)NB * NA * 8;

    // zero lg+gg+cnt (contiguous): (114688+7168)*4 + 896*4 = 491008 B
    hipMemsetAsync(d_ws, 0, 491008, stream);

    risnet_fused<<<dim3(1024), dim3(256), 0, stream>>>(
        channel, W1, b1, Wm, bm, W8, b8, (float*)d_out,
        lg, gg, gl1, gl3, cnt);
}

// Round 7
// 1477.684 us; speedup vs baseline: 1.9775x; 1.9775x over previous
//
#include <hip/hip_runtime.h>

// RISnetPIv2 fully-fused persistent kernel, v2. B=128, U=16, A=1024.
// ll tile lives in LDS (not registers - r6's llp[32] + cgl[32] overflowed the
// VGPR budget -> 2.9GB scratch spill traffic). f3 skip tile in GLOBAL ws
// (+67MB traffic ~= 10us, vs 32KB LDS it would cost). Grid 1024 = 128 b x 8
// a-blocks; block 256 = 128 a x 2 u-halves; thread owns (a, 8 u's, 32 ch).
// LDS 40576 B -> 4 blocks/CU; launch_bounds(256,4); per-b 8-block spin
// barrier between layers (proven correct in r6).

#define NB 128
#define NU 16
#define NA 1024

static constexpr float PI_F   = 3.14159265358979323846f;
static constexpr float INV_A  = 1.0f / 1024.0f;
static constexpr float INV_UA = 1.0f / 16384.0f;
static constexpr float INV_U  = 1.0f / 16.0f;

__device__ __forceinline__ float wsum(float v) {
#pragma unroll
    for (int d = 1; d < 64; d <<= 1) v += __shfl_xor(v, d, 64);
    return v;
}
__device__ __forceinline__ unsigned short f2bf(float f) {  // RNE
    unsigned int u = __float_as_uint(f);
    u += 0x7fffu + ((u >> 16) & 1u);
    return (unsigned short)(u >> 16);
}
__device__ __forceinline__ unsigned int pack2(float a, float b) {
    return (unsigned int)f2bf(a) | ((unsigned int)f2bf(b) << 16);
}
__device__ __forceinline__ float bflo(unsigned int u) { return __uint_as_float(u << 16); }
__device__ __forceinline__ float bfhi(unsigned int u) { return __uint_as_float(u & 0xffff0000u); }
__device__ __forceinline__ float aload(float* p) {
    return __hip_atomic_load(p, __ATOMIC_RELAXED, __HIP_MEMORY_SCOPE_AGENT);
}

__device__ __forceinline__ void spin_wait(int* cnt, int idx, int tid) {
    if (tid == 0) {
        int it = 0;
        while (__hip_atomic_load(cnt + idx, __ATOMIC_ACQUIRE,
                                 __HIP_MEMORY_SCOPE_AGENT) < 8) {
            __builtin_amdgcn_s_sleep(2);
            if (++it > (1 << 22)) break;  // safety valve
        }
    }
    __syncthreads();
}

// gg butterfly+atomic, lg combine+atomic, glds update (+snapshot), release.
__device__ __forceinline__ void layer_tail(
    int li, int b, int a, int aIdx, int uh, int tid,
    const float* glacc, const float* ggacc,
    float* red, float* glds,
    float* lg, float* gg, int* cnt, float* snap)
{
#pragma unroll
    for (int c = 0; c < 8; ++c) {
        float v = wsum(ggacc[c]);
        if ((tid & 63) == 0) atomicAdd(gg + (li * NB + b) * 8 + c, v);
    }
    __syncthreads();                       // red lg-partials complete
    if (tid < 128) {
        int u = tid >> 3, c = tid & 7;
        int base = (u < 8 ? 0 : 2) * 64 + (u & 7) * 8 + c;
        float v = red[base] + red[base + 64];
        atomicAdd(lg + ((size_t)(li * NB + b) * NU + u) * 8 + c, v);
    }
    __syncthreads();
    if (uh == 1) {
#pragma unroll
        for (int c = 0; c < 8; ++c) glds[aIdx * 9 + c] = glacc[c];
    }
    __syncthreads();
    if (uh == 0) {
#pragma unroll
        for (int c = 0; c < 8; ++c) {
            float g = (glacc[c] + glds[aIdx * 9 + c]) * INV_U;
            glds[aIdx * 9 + c] = g;
            if (snap) snap[((size_t)b * NA + a) * 8 + c] = g;
        }
    }
    __threadfence();
    __syncthreads();
    if (tid == 0)
        __hip_atomic_fetch_add(cnt + li * NB + b, 1, __ATOMIC_RELEASE,
                               __HIP_MEMORY_SCOPE_AGENT);
}

__global__ __launch_bounds__(256, 4) void risnet_fused(
    const float* __restrict__ ch, const float* __restrict__ W1,
    const float* __restrict__ b1, const float* __restrict__ Wm,
    const float* __restrict__ bm, const float* __restrict__ W8,
    const float* __restrict__ b8, float* __restrict__ out,
    float* lg, float* gg, float* gl1, float* gl3,
    unsigned int* f3g, int* cnt)
{
    __shared__ unsigned int llds[16 * 128 * 4];  // 32768 B: ll tile, packed bf16
    __shared__ float glds[128 * 9];              //  4608 B: gl (mean), padded
    __shared__ float baseds[16 * 32];            //  2048 B
    __shared__ float red[288];                   //  1152 B   (total 40576)

    const int tid  = threadIdx.x;
    const int aIdx = tid & 127;
    const int uh   = tid >> 7;
    const int wv   = tid >> 6;
    const int b    = blockIdx.x >> 3;
    const int ab   = blockIdx.x & 7;
    const int a    = ab * 128 + aIdx;
    const int u0   = uh * 8;

    float glacc[8], ggacc[8];

    // ================= Layer 1 =================
    {
#pragma unroll
        for (int i = 0; i < 8; ++i) { glacc[i] = 0.f; ggacc[i] = 0.f; }
#pragma unroll 2
        for (int ul = 0; ul < 8; ++ul) {
            const int u = u0 + ul;
            float x[4];
#pragma unroll
            for (int c = 0; c < 4; ++c)
                x[c] = ch[((size_t)(b * 4 + c) * NU + u) * NA + a];

            float yA[16];
#pragma unroll
            for (int o = 0; o < 16; ++o) yA[o] = b1[o];
#pragma unroll
            for (int c = 0; c < 4; ++c) {
#pragma unroll
                for (int o = 0; o < 16; ++o)
                    yA[o] = fmaf(x[c], W1[((o >> 3) * 4 + c) * 8 + (o & 7)], yA[o]);
            }
#pragma unroll
            for (int o = 0; o < 16; ++o) yA[o] = fmaxf(yA[o], 0.f);
            {
                uint4 v;
                v.x = pack2(yA[0], yA[1]); v.y = pack2(yA[2], yA[3]);
                v.z = pack2(yA[4], yA[5]); v.w = pack2(yA[6], yA[7]);
                *reinterpret_cast<uint4*>(&llds[(u * 128 + aIdx) * 4]) = v;
            }
#pragma unroll
            for (int c = 0; c < 8; ++c) {
                float v = wsum(yA[8 + c]);
                if ((tid & 63) == 0) red[wv * 64 + ul * 8 + c] = v;
            }
            float yB[16];
#pragma unroll
            for (int o = 0; o < 16; ++o) yB[o] = b1[o + 16];
#pragma unroll
            for (int c = 0; c < 4; ++c) {
#pragma unroll
                for (int o = 0; o < 16; ++o)
                    yB[o] = fmaf(x[c], W1[((2 + (o >> 3)) * 4 + c) * 8 + (o & 7)], yB[o]);
            }
#pragma unroll
            for (int o = 0; o < 16; ++o) yB[o] = fmaxf(yB[o], 0.f);
#pragma unroll
            for (int i = 0; i < 8; ++i) { glacc[i] += yB[i]; ggacc[i] += yB[8 + i]; }
        }
        layer_tail(0, b, a, aIdx, uh, tid, glacc, ggacc, red, glds, lg, gg, cnt, gl1);
    }

    // ================= Layers 2..7 =================
#pragma unroll 1
    for (int li = 1; li <= 6; ++li) {
        const bool isL3 = (li == 2), isL5 = (li == 4), isL6 = (li == 5);
        const float* Wl = Wm + (size_t)(li - 1) * 1024;
        const float* bl = bm + (size_t)(li - 1) * 32;

        spin_wait(cnt, (li - 1) * NB + b, tid);

        // stage lg/gg MEANS into red[0..135]
        if (tid < 136) {
            float v;
            if (tid < 128) {
                int u = tid >> 3, c = tid & 7;
                v = aload(lg + ((size_t)((li - 1) * NB + b) * NU + u) * 8 + c) * INV_A;
                if (isL6)
                    v = (v + aload(lg + ((size_t)b * NU + u) * 8 + c) * INV_A) * 0.5f;
            } else {
                int c = tid - 128;
                v = aload(gg + ((li - 1) * NB + b) * 8 + c) * INV_UA;
                if (isL6) v = (v + aload(gg + b * 8 + c) * INV_UA) * 0.5f;
            }
            red[tid] = v;
        }
        // cgl[32] from glds (+ L6 skip with gl1 snapshot)
        float g[8];
#pragma unroll
        for (int c = 0; c < 8; ++c) g[c] = glds[aIdx * 9 + c];
        if (isL6) {
#pragma unroll
            for (int c = 0; c < 8; ++c)
                g[c] = (g[c] + gl1[((size_t)b * NA + a) * 8 + c]) * 0.5f;
        }
        float cgl[32];
#pragma unroll
        for (int o = 0; o < 32; ++o) cgl[o] = 0.f;
#pragma unroll
        for (int c = 0; c < 8; ++c) {
#pragma unroll
            for (int o = 0; o < 32; ++o)
                cgl[o] = fmaf(g[c], Wl[((o >> 3) * 32 + 16 + c) * 8 + (o & 7)], cgl[o]);
        }
        __syncthreads();
        // base[16][32]
        {
            int u = tid >> 4, op = tid & 15;
#pragma unroll
            for (int h = 0; h < 2; ++h) {
                int o = op + h * 16;
                float v = bl[o];
#pragma unroll
                for (int c = 0; c < 8; ++c)
                    v = fmaf(red[u * 8 + c], Wl[((o >> 3) * 32 + 8 + c) * 8 + (o & 7)], v);
#pragma unroll
                for (int c = 0; c < 8; ++c)
                    v = fmaf(red[128 + c], Wl[((o >> 3) * 32 + 24 + c) * 8 + (o & 7)], v);
                baseds[u * 32 + o] = v;
            }
        }
        __syncthreads();

#pragma unroll
        for (int i = 0; i < 8; ++i) { glacc[i] = 0.f; ggacc[i] = 0.f; }
#pragma unroll 2
        for (int ul = 0; ul < 8; ++ul) {
            const int u = u0 + ul;
            float x[8];
            {
                uint4 v = *reinterpret_cast<const uint4*>(&llds[(u * 128 + aIdx) * 4]);
                x[0] = bflo(v.x); x[1] = bfhi(v.x);
                x[2] = bflo(v.y); x[3] = bfhi(v.y);
                x[4] = bflo(v.z); x[5] = bfhi(v.z);
                x[6] = bflo(v.w); x[7] = bfhi(v.w);
            }
            float yA[16];
#pragma unroll
            for (int o = 0; o < 16; ++o) yA[o] = cgl[o] + baseds[u * 32 + o];
#pragma unroll
            for (int c = 0; c < 8; ++c) {
#pragma unroll
                for (int o = 0; o < 16; ++o)
                    yA[o] = fmaf(x[c], Wl[((o >> 3) * 32 + c) * 8 + (o & 7)], yA[o]);
            }
#pragma unroll
            for (int o = 0; o < 16; ++o) yA[o] = fmaxf(yA[o], 0.f);

            float o8[8];
            if (isL5) {   // average with recomputed f1 ll (branch 0 of layer 1)
                float t[8];
#pragma unroll
                for (int i = 0; i < 8; ++i) t[i] = b1[i];
#pragma unroll
                for (int c = 0; c < 4; ++c) {
                    float xc = ch[((size_t)(b * 4 + c) * NU + u) * NA + a];
#pragma unroll
                    for (int i = 0; i < 8; ++i)
                        t[i] = fmaf(xc, W1[c * 8 + i], t[i]);
                }
#pragma unroll
                for (int i = 0; i < 8; ++i)
                    o8[i] = (yA[i] + fmaxf(t[i], 0.f)) * 0.5f;
            } else {
#pragma unroll
                for (int i = 0; i < 8; ++i) o8[i] = yA[i];
            }
            {
                uint4 v;
                v.x = pack2(o8[0], o8[1]); v.y = pack2(o8[2], o8[3]);
                v.z = pack2(o8[4], o8[5]); v.w = pack2(o8[6], o8[7]);
                *reinterpret_cast<uint4*>(&llds[(u * 128 + aIdx) * 4]) = v;
                if (isL3)   // pin f3 ll to global
                    *reinterpret_cast<uint4*>(
                        f3g + ((size_t)(b * NU + u) * NA + a) * 4) = v;
            }
#pragma unroll
            for (int c = 0; c < 8; ++c) {
                float v = wsum(yA[8 + c]);
                if ((tid & 63) == 0) red[wv * 64 + ul * 8 + c] = v;
            }
            float yB[16];
#pragma unroll
            for (int o = 0; o < 16; ++o) yB[o] = cgl[o + 16] + baseds[u * 32 + 16 + o];
#pragma unroll
            for (int c = 0; c < 8; ++c) {
#pragma unroll
                for (int o = 0; o < 16; ++o)
                    yB[o] = fmaf(x[c], Wl[((2 + (o >> 3)) * 32 + c) * 8 + (o & 7)], yB[o]);
            }
#pragma unroll
            for (int o = 0; o < 16; ++o) yB[o] = fmaxf(yB[o], 0.f);
#pragma unroll
            for (int i = 0; i < 8; ++i) { glacc[i] += yB[i]; ggacc[i] += yB[8 + i]; }
        }
        layer_tail(li, b, a, aIdx, uh, tid, glacc, ggacc, red, glds, lg, gg, cnt,
                   isL3 ? gl3 : nullptr);
    }

    // ================= Layer 8 =================
    spin_wait(cnt, 6 * NB + b, tid);
    if (tid < 8) {
        int c = tid;
        float s7 = 0.f, s3 = 0.f;
#pragma unroll
        for (int u = 0; u < NU; ++u) {
            s7 += aload(lg + ((size_t)(6 * NB + b) * NU + u) * 8 + c);
            s3 += aload(lg + ((size_t)(2 * NB + b) * NU + u) * 8 + c);
        }
        float g7 = aload(gg + (6 * NB + b) * 8 + c);
        float g3 = aload(gg + (2 * NB + b) * 8 + c);
        red[256 + c] = ((s7 + s3) * INV_A * 0.5f * INV_U) * W8[8 + c]
                     + ((g7 + g3) * INV_UA * 0.5f) * W8[24 + c];
    }
    float p = 0.f;
#pragma unroll 2
    for (int ul = 0; ul < 8; ++ul) {
        const int u = u0 + ul;
        uint4 f3v = *reinterpret_cast<const uint4*>(
            f3g + ((size_t)(b * NU + u) * NA + a) * 4);
        uint4 w7v = *reinterpret_cast<const uint4*>(&llds[(u * 128 + aIdx) * 4]);
        unsigned int w3[4] = {f3v.x, f3v.y, f3v.z, f3v.w};
        unsigned int w7[4] = {w7v.x, w7v.y, w7v.z, w7v.w};
#pragma unroll
        for (int cp = 0; cp < 4; ++cp) {
            p += 0.5f * (bflo(w7[cp]) + bflo(w3[cp])) * W8[cp * 2]
               + 0.5f * (bfhi(w7[cp]) + bfhi(w3[cp])) * W8[cp * 2 + 1];
        }
    }
    red[tid] = p;
    __syncthreads();
    if (uh == 0) {
        float asum = (red[tid] + red[tid + 128]) * INV_U;
        float sb = b8[0];
#pragma unroll
        for (int c = 0; c < 8; ++c) sb += red[256 + c];
#pragma unroll
        for (int c = 0; c < 8; ++c)
            asum += 0.5f * (glds[aIdx * 9 + c] + gl3[((size_t)b * NA + a) * 8 + c])
                  * W8[16 + c];
        out[(size_t)b * NA + a] = (asum + sb) * PI_F;
    }
}

extern "C" void kernel_launch(void* const* d_in, const int* in_sizes, int n_in,
                              void* d_out, int out_size, void* d_ws, size_t ws_size,
                              hipStream_t stream) {
    const float* channel = (const float*)d_in[0];
    const float* W1 = (const float*)d_in[1];
    const float* b1 = (const float*)d_in[2];
    const float* Wm = (const float*)d_in[3];
    const float* bm = (const float*)d_in[4];
    const float* W8 = (const float*)d_in[5];
    const float* b8 = (const float*)d_in[6];

    float* lg = (float*)d_ws;                    // [7][128][16][8] = 114688 f
    float* gg = lg + 7 * NB * NU * 8;            // [7][128][8]     = 7168 f
    int* cnt  = (int*)(gg + 7 * NB * 8);         // [7][128]        = 896 i
    float* gl1 = (float*)(cnt + 7 * NB);         // [128][1024][8] f
    float* gl3 = gl1 + (size_t)NB * NA * 8;      // [128][1024][8] f
    unsigned int* f3g = (unsigned int*)(gl3 + (size_t)NB * NA * 8);  // 8M uints

    // zero lg+gg+cnt (contiguous): (114688+7168+896)*4 = 491008 B
    hipMemsetAsync(d_ws, 0, 491008, stream);

    risnet_fused<<<dim3(1024), dim3(256), 0, stream>>>(
        channel, W1, b1, Wm, bm, W8, b8, (float*)d_out,
        lg, gg, gl1, gl3, f3g, cnt);
}